// Round 1
// baseline (965.466 us; speedup 1.0000x reference)
//
#include <hip/hip_runtime.h>

#define B_N   8
#define T_N   32768
#define RESC  128
#define GATEC 256
#define CINC  80
#define CINP  96
#define NT    64
#define HALO  4
#define XROWS 68

#define XSTR_B 272           /* x-tile byte stride: 136 ushorts */
#define CSTR_B 208           /* cond-tile byte stride: 104 ushorts (pad kills 8-way) */
#define CS_OFF 18496         /* 68*272 bytes */
#define LDS_BYTES (18496 + 13312)   /* xs + cs = 31808 B -> 5 blocks/CU */

#define AP1_ELEMS (16*12*512)  /* 98304 bf16 */
#define AP2_ELEMS (16*3*512)   /* 24576 */
#define AP3_ELEMS (16*4*512)   /* 32768 */

#define OFF_S ((size_t)B_N * RESC * T_N)  /* s output offset in floats */

typedef __attribute__((ext_vector_type(8))) short short8;
typedef __attribute__((ext_vector_type(4))) float f32x4;

__device__ __forceinline__ ushort f2bf(float f) {
  union { float f; unsigned int u; } c; c.f = f;
  unsigned int u = c.u;
  u += 0x7fffu + ((u >> 16) & 1u);   // round-to-nearest-even
  return (ushort)(u >> 16);
}

// XOR-swizzled LDS addressing. Bijective within each 8-row group because
// 8*stride is a multiple of 128 B for both strides used (272, 208).
// Flips byte-addr bits [4:6] -> spreads the 8 t-groups of a staging wave
// across 8 bank quads (was 8-way conflict), keeps 16B blocks intact so
// ds_read_b128 stays legal. Same formula on write and read.
__device__ __forceinline__ char* lds_at(char* base, int row, int strB, int colB) {
  int off = row * strB + colB;
  off ^= ((row >> 3) & 7) << 4;
  return base + off;
}

// ---------------------------------------------------------------------------
// Prep: weight-norm (fp32) -> bf16 -> pack into MFMA A-fragment order.
// A-frag layout (16x16x32 bf16, m89-verified): A[m = lane&15][k = (lane>>4)*8 + j]
// Apack[((mtile*KS + ks)*64 + lane)*8 + j]
// ---------------------------------------------------------------------------
__global__ __launch_bounds__(256) void wn_pack_kernel(
    const float* __restrict__ conv_v, const float* __restrict__ conv_g,
    const float* __restrict__ lc_v,  const float* __restrict__ lc_g,
    const float* __restrict__ skip_v,const float* __restrict__ skip_g,
    const float* __restrict__ out_v, const float* __restrict__ out_g,
    ushort* __restrict__ Ap1, ushort* __restrict__ Ap2, ushort* __restrict__ Ap3) {
  const int o   = blockIdx.x;   // output channel 0..255
  const int tid = threadIdx.x;  // 0..255
  const int mtg = o >> 4, r = o & 15;
  __shared__ float red[256];

  // ---- conv: norm over 128*3 ----
  float s = 0.f;
  for (int e = tid; e < RESC * 3; e += 256) { float v = conv_v[o * RESC * 3 + e]; s += v * v; }
  red[tid] = s; __syncthreads();
  for (int off = 128; off > 0; off >>= 1) { if (tid < off) red[tid] += red[tid + off]; __syncthreads(); }
  const float csc = conv_g[o] / sqrtf(red[0]);
  __syncthreads();
  for (int e = tid; e < 384; e += 256) {
    const int ks = e >> 5, q = (e >> 3) & 3, j = e & 7;
    const int tap = ks >> 2, ci = (ks & 3) * 32 + q * 8 + j;
    Ap1[((mtg * 12 + ks) * 64 + q * 16 + r) * 8 + j] = f2bf(conv_v[(o * RESC + ci) * 3 + tap] * csc);
  }

  // ---- lc: norm over 80, pad K to 96 ----
  s = 0.f;
  for (int e = tid; e < CINC; e += 256) { float v = lc_v[o * CINC + e]; s += v * v; }
  red[tid] = s; __syncthreads();
  for (int off = 128; off > 0; off >>= 1) { if (tid < off) red[tid] += red[tid + off]; __syncthreads(); }
  const float lsc = lc_g[o] / sqrtf(red[0]);
  __syncthreads();
  for (int e = tid; e < CINP; e += 256) {
    const int ks = e >> 5, q = (e >> 3) & 3, j = e & 7;
    const float wv = (e < CINC) ? lc_v[o * CINC + e] * lsc : 0.f;
    Ap2[((mtg * 3 + ks) * 64 + q * 16 + r) * 8 + j] = f2bf(wv);
  }

  // ---- skip (rows 0..127) / out (rows 128..255): norm over 128 ----
  const float* vrow = (o < 128) ? (skip_v + o * 128) : (out_v + (o - 128) * 128);
  const float  gg   = (o < 128) ? skip_g[o] : out_g[o - 128];
  s = 0.f;
  for (int e = tid; e < 128; e += 256) { float v = vrow[e]; s += v * v; }
  red[tid] = s; __syncthreads();
  for (int off = 128; off > 0; off >>= 1) { if (tid < off) red[tid] += red[tid + off]; __syncthreads(); }
  const float ssc = gg / sqrtf(red[0]);
  for (int e = tid; e < 128; e += 256) {
    const int ks = e >> 5, q = (e >> 3) & 3, j = e & 7;
    Ap3[((mtg * 4 + ks) * 64 + q * 16 + r) * 8 + j] = f2bf(vrow[e] * ssc);
  }
}

// ---------------------------------------------------------------------------
// Fused block: conv(dil=2,causal) + cond GEMM -> gate (in-register) ->
// skip/out GEMMs. Grid: 4096 = 8 batches x 512 time-tiles of 64.
// Block: 256 thr = 4 waves.
// GEMM1/2: wave w owns PAIRED gate channels: a-mtiles {2w,2w+1} (h rows
// 32w..32w+31) and b-mtiles {8+2w,9+2w} (h rows 128+32w..). tanh*sigmoid is
// then computed wave-locally in f32 registers -> one LDS write of g, one
// barrier (was: two activation phases + product phase + 2 barriers).
// GEMM3: wave w owns output rows 64w.. (waves 0,1 skip; 2,3 out) as before.
// ---------------------------------------------------------------------------
__global__ __launch_bounds__(256, 5) void fused_block_kernel(
    const float* __restrict__ x, const float* __restrict__ cond,
    const float* __restrict__ conv_b, const float* __restrict__ skip_b,
    const float* __restrict__ out_b,
    const ushort* __restrict__ Ap1, const ushort* __restrict__ Ap2,
    const ushort* __restrict__ Ap3,
    float* __restrict__ out) {
  const int tid  = threadIdx.x;
  const int w    = tid >> 6;
  const int lane = tid & 63;
  const int q    = lane >> 4;   // MFMA quad
  const int n    = lane & 15;   // MFMA column (time within 16-tile)
  const int blk  = blockIdx.x;
  const int b    = blk >> 9;
  const int t0   = (blk & 511) << 6;

  __shared__ __align__(128) char smem[LDS_BYTES];
  char* xs = smem;            // [68][136 ushort] x-tile (rows = t - (t0-4)), swizzled
  char* cs = smem + CS_OFF;   // [64][104 ushort] cond-tile, swizzled
  char* gs = smem;            // [64][136 ushort] g-tile, aliases xs after barrier

  // ================= stage x tile (transpose [c][t] -> [t][c], bf16) =======
  {
    const int g4 = tid >> 3;            // 0..31 -> channels 4*g4..+3
    const int c0 = g4 << 2;
    const int tt = (tid & 7) << 3;      // 8 timesteps per thread
    const float* xp = x + ((size_t)b * RESC + c0) * T_N + t0 + tt;
    float va[4][8];
#pragma unroll
    for (int rr = 0; rr < 4; ++rr) {
      const float4* rp = (const float4*)(xp + (size_t)rr * T_N);
      const float4 a0 = rp[0], a1 = rp[1];
      va[rr][0] = a0.x; va[rr][1] = a0.y; va[rr][2] = a0.z; va[rr][3] = a0.w;
      va[rr][4] = a1.x; va[rr][5] = a1.y; va[rr][6] = a1.z; va[rr][7] = a1.w;
    }
#pragma unroll
    for (int ss = 0; ss < 8; ++ss) {
      const unsigned lo = (unsigned)f2bf(va[0][ss]) | ((unsigned)f2bf(va[1][ss]) << 16);
      const unsigned hi = (unsigned)f2bf(va[2][ss]) | ((unsigned)f2bf(va[3][ss]) << 16);
      *(uint2*)lds_at(xs, HALO + tt + ss, XSTR_B, c0 * 2) = make_uint2(lo, hi);
    }
  }
  // halo rows 0..3 = t0-4..t0-1 (zeros at sequence start = causal left-pad)
  if (tid < RESC) {
    float h0 = 0.f, h1 = 0.f, h2 = 0.f, h3 = 0.f;
    if (t0 > 0) {
      const float4 hv = *(const float4*)(x + ((size_t)b * RESC + tid) * T_N + t0 - 4);
      h0 = hv.x; h1 = hv.y; h2 = hv.z; h3 = hv.w;
    }
    *(ushort*)lds_at(xs, 0, XSTR_B, tid * 2) = f2bf(h0);
    *(ushort*)lds_at(xs, 1, XSTR_B, tid * 2) = f2bf(h1);
    *(ushort*)lds_at(xs, 2, XSTR_B, tid * 2) = f2bf(h2);
    *(ushort*)lds_at(xs, 3, XSTR_B, tid * 2) = f2bf(h3);
  }
  // ================= stage cond tile ([c][t] -> [t][c], pad 80->96) ========
  if (tid < 160) {
    const int g4 = tid >> 3;            // 0..19
    const int c0 = g4 << 2;
    const int tt = (tid & 7) << 3;
    const float* cp = cond + ((size_t)b * CINC + c0) * T_N + t0 + tt;
    float va[4][8];
#pragma unroll
    for (int rr = 0; rr < 4; ++rr) {
      const float4* rp = (const float4*)(cp + (size_t)rr * T_N);
      const float4 a0 = rp[0], a1 = rp[1];
      va[rr][0] = a0.x; va[rr][1] = a0.y; va[rr][2] = a0.z; va[rr][3] = a0.w;
      va[rr][4] = a1.x; va[rr][5] = a1.y; va[rr][6] = a1.z; va[rr][7] = a1.w;
    }
#pragma unroll
    for (int ss = 0; ss < 8; ++ss) {
      const unsigned lo = (unsigned)f2bf(va[0][ss]) | ((unsigned)f2bf(va[1][ss]) << 16);
      const unsigned hi = (unsigned)f2bf(va[2][ss]) | ((unsigned)f2bf(va[3][ss]) << 16);
      *(uint2*)lds_at(cs, tt + ss, CSTR_B, c0 * 2) = make_uint2(lo, hi);
    }
  } else {
    const int e0 = tid - 160;           // zero-fill ushort cols 80..95 (k-pad)
    for (int z = e0; z < 512; z += 96) {
      const int row = z >> 3, c = z & 7;
      *(unsigned int*)lds_at(cs, row, CSTR_B, 160 + c * 4) = 0u;
    }
  }
  __syncthreads();

  // ================= GEMM1 (conv, K=384) + GEMM2 (lc, K=96) into acc ======
  // acc[0..1] = a-half (h rows 32w + 16*mt + ...), acc[2..3] = b-half.
  const int mtile[4] = {2 * w, 2 * w + 1, 8 + 2 * w, 9 + 2 * w};
  f32x4 acc[4][4];
#pragma unroll
  for (int mt = 0; mt < 4; ++mt) {
    const float4 cb = *(const float4*)(conv_b + mtile[mt] * 16 + q * 4);
#pragma unroll
    for (int nt = 0; nt < 4; ++nt) acc[mt][nt] = (f32x4){cb.x, cb.y, cb.z, cb.w};
  }
#pragma unroll
  for (int ks = 0; ks < 12; ++ks) {
    const int tap = ks >> 2;
    const int cbyte = ((ks & 3) << 6);
    short8 af[4], bfr[4];
#pragma unroll
    for (int mt = 0; mt < 4; ++mt)
      af[mt] = *(const short8*)(Ap1 + ((mtile[mt] * 12 + ks) * 64 + lane) * 8);
#pragma unroll
    for (int nt = 0; nt < 4; ++nt)
      bfr[nt] = *(const short8*)lds_at(xs, nt * 16 + n + tap * 2, XSTR_B, cbyte + q * 16);
#pragma unroll
    for (int mt = 0; mt < 4; ++mt)
#pragma unroll
      for (int nt = 0; nt < 4; ++nt)
        acc[mt][nt] = __builtin_amdgcn_mfma_f32_16x16x32_bf16(af[mt], bfr[nt], acc[mt][nt], 0, 0, 0);
  }
#pragma unroll
  for (int ks = 0; ks < 3; ++ks) {
    short8 af[4], bfr[4];
#pragma unroll
    for (int mt = 0; mt < 4; ++mt)
      af[mt] = *(const short8*)(Ap2 + ((mtile[mt] * 3 + ks) * 64 + lane) * 8);
#pragma unroll
    for (int nt = 0; nt < 4; ++nt)
      bfr[nt] = *(const short8*)lds_at(cs, nt * 16 + n, CSTR_B, ks * 64 + q * 16);
#pragma unroll
    for (int mt = 0; mt < 4; ++mt)
#pragma unroll
      for (int nt = 0; nt < 4; ++nt)
        acc[mt][nt] = __builtin_amdgcn_mfma_f32_16x16x32_bf16(af[mt], bfr[nt], acc[mt][nt], 0, 0, 0);
  }
  __syncthreads();   // all xs/cs reads done; safe to overwrite aliased region

  // ================= g = tanh(a)*sigmoid(b) in registers -> LDS ===========
#pragma unroll
  for (int mt = 0; mt < 2; ++mt)
#pragma unroll
    for (int nt = 0; nt < 4; ++nt) {
      const f32x4 va = acc[mt][nt];
      const f32x4 vb = acc[mt + 2][nt];
      float r[4];
#pragma unroll
      for (int i = 0; i < 4; ++i) {
        const float ta = 1.f - 2.f / (__expf(2.f * va[i]) + 1.f);
        const float sb = 1.f / (1.f + __expf(-vb[i]));
        r[i] = ta * sb;
      }
      const unsigned lo = (unsigned)f2bf(r[0]) | ((unsigned)f2bf(r[1]) << 16);
      const unsigned hi = (unsigned)f2bf(r[2]) | ((unsigned)f2bf(r[3]) << 16);
      // gate channel = 32w + 16*mt + 4*q + i ; byte col = 2*channel
      *(uint2*)lds_at(gs, nt * 16 + n, XSTR_B, 64 * w + 32 * mt + 8 * q) = make_uint2(lo, hi);
    }
  __syncthreads();

  // ================= GEMM3: [skip;out] = Wso @ g, K=128 ===================
  const int colbase = (w & 1) << 6;
  {
    const float* bias = (w < 2) ? skip_b : out_b;
#pragma unroll
    for (int mt = 0; mt < 4; ++mt) {
      const float4 bb = *(const float4*)(bias + colbase + mt * 16 + q * 4);
#pragma unroll
      for (int nt = 0; nt < 4; ++nt) acc[mt][nt] = (f32x4){bb.x, bb.y, bb.z, bb.w};
    }
#pragma unroll
    for (int ks = 0; ks < 4; ++ks) {
      short8 af[4], bfr[4];
#pragma unroll
      for (int mt = 0; mt < 4; ++mt)
        af[mt] = *(const short8*)(Ap3 + ((w * 4 + mt) * 4 + ks) * 512 + lane * 8);
#pragma unroll
      for (int nt = 0; nt < 4; ++nt)
        bfr[nt] = *(const short8*)lds_at(gs, nt * 16 + n, XSTR_B, ks * 64 + q * 16);
#pragma unroll
      for (int mt = 0; mt < 4; ++mt)
#pragma unroll
        for (int nt = 0; nt < 4; ++nt)
          acc[mt][nt] = __builtin_amdgcn_mfma_f32_16x16x32_bf16(af[mt], bfr[nt], acc[mt][nt], 0, 0, 0);
    }
  }

  // ================= epilogue: stores (s for waves 0,1; o+residual 2,3) ===
#pragma unroll
  for (int mt = 0; mt < 4; ++mt)
#pragma unroll
    for (int nt = 0; nt < 4; ++nt) {
      const int ch = colbase + mt * 16 + q * 4;
      const int t  = t0 + nt * 16 + n;
      const f32x4 v = acc[mt][nt];
      if (w < 2) {
        float* dst = out + OFF_S + ((size_t)(b * RESC + ch)) * T_N + t;
#pragma unroll
        for (int i = 0; i < 4; ++i) dst[(size_t)i * T_N] = v[i];
      } else {
        const float* xr = x + ((size_t)(b * RESC + ch)) * T_N + t;
        float* dst = out + ((size_t)(b * RESC + ch)) * T_N + t;
#pragma unroll
        for (int i = 0; i < 4; ++i) dst[(size_t)i * T_N] = v[i] + xr[(size_t)i * T_N];
      }
    }
}

extern "C" void kernel_launch(void* const* d_in, const int* in_sizes, int n_in,
                              void* d_out, int out_size, void* d_ws, size_t ws_size,
                              hipStream_t stream) {
  const float* x      = (const float*)d_in[0];
  const float* cond   = (const float*)d_in[1];
  const float* conv_v = (const float*)d_in[2];
  const float* conv_g = (const float*)d_in[3];
  const float* conv_b = (const float*)d_in[4];
  const float* lc_v   = (const float*)d_in[5];
  const float* lc_g   = (const float*)d_in[6];
  const float* skip_v = (const float*)d_in[7];
  const float* skip_g = (const float*)d_in[8];
  const float* skip_b = (const float*)d_in[9];
  const float* out_v  = (const float*)d_in[10];
  const float* out_g  = (const float*)d_in[11];
  const float* out_b  = (const float*)d_in[12];

  ushort* Ap1 = (ushort*)d_ws;
  ushort* Ap2 = Ap1 + AP1_ELEMS;
  ushort* Ap3 = Ap2 + AP2_ELEMS;

  hipLaunchKernelGGL(wn_pack_kernel, dim3(256), dim3(256), 0, stream,
                     conv_v, conv_g, lc_v, lc_g, skip_v, skip_g, out_v, out_g,
                     Ap1, Ap2, Ap3);
  hipLaunchKernelGGL(fused_block_kernel, dim3(4096), dim3(256), 0, stream,
                     x, cond, conv_b, skip_b, out_b, Ap1, Ap2, Ap3, (float*)d_out);
}

// Round 2
// 543.301 us; speedup vs baseline: 1.7770x; 1.7770x over previous
//
#include <hip/hip_runtime.h>

#define B_N   8
#define T_N   32768
#define RESC  128
#define GATEC 256
#define CINC  80
#define CINP  96
#define NT    64
#define HALO  4
#define XROWS 68

#define XSTR_B 272           /* x-tile byte stride: 136 ushorts */
#define CSTR_B 208           /* cond-tile byte stride: 104 ushorts (pad kills 8-way) */
#define CS_OFF 18496         /* 68*272 bytes */
#define LDS_BYTES (18496 + 13312)   /* xs + cs = 31808 B */

#define AP1_ELEMS (16*12*512)  /* 98304 bf16 */
#define AP2_ELEMS (16*3*512)   /* 24576 */
#define AP3_ELEMS (16*4*512)   /* 32768 */

#define OFF_S ((size_t)B_N * RESC * T_N)  /* s output offset in floats */

typedef __attribute__((ext_vector_type(8))) short short8;
typedef __attribute__((ext_vector_type(4))) float f32x4;

__device__ __forceinline__ ushort f2bf(float f) {
  union { float f; unsigned int u; } c; c.f = f;
  unsigned int u = c.u;
  u += 0x7fffu + ((u >> 16) & 1u);   // round-to-nearest-even
  return (ushort)(u >> 16);
}

// XOR-swizzled LDS addressing. Bijective within each 8-row group because
// 8*stride is a multiple of 128 B for both strides used (272, 208).
// Flips byte-addr bits [4:6] -> spreads the 8 t-groups of a staging wave
// across 8 bank quads (was 8-way conflict), keeps 16B blocks intact so
// ds_read_b128 stays legal. Same formula on write and read.
__device__ __forceinline__ char* lds_at(char* base, int row, int strB, int colB) {
  int off = row * strB + colB;
  off ^= ((row >> 3) & 7) << 4;
  return base + off;
}

// ---------------------------------------------------------------------------
// Prep: weight-norm (fp32) -> bf16 -> pack into MFMA A-fragment order.
// A-frag layout (16x16x32 bf16, m89-verified): A[m = lane&15][k = (lane>>4)*8 + j]
// Apack[((mtile*KS + ks)*64 + lane)*8 + j]
// ---------------------------------------------------------------------------
__global__ __launch_bounds__(256) void wn_pack_kernel(
    const float* __restrict__ conv_v, const float* __restrict__ conv_g,
    const float* __restrict__ lc_v,  const float* __restrict__ lc_g,
    const float* __restrict__ skip_v,const float* __restrict__ skip_g,
    const float* __restrict__ out_v, const float* __restrict__ out_g,
    ushort* __restrict__ Ap1, ushort* __restrict__ Ap2, ushort* __restrict__ Ap3) {
  const int o   = blockIdx.x;   // output channel 0..255
  const int tid = threadIdx.x;  // 0..255
  const int mtg = o >> 4, r = o & 15;
  __shared__ float red[256];

  // ---- conv: norm over 128*3 ----
  float s = 0.f;
  for (int e = tid; e < RESC * 3; e += 256) { float v = conv_v[o * RESC * 3 + e]; s += v * v; }
  red[tid] = s; __syncthreads();
  for (int off = 128; off > 0; off >>= 1) { if (tid < off) red[tid] += red[tid + off]; __syncthreads(); }
  const float csc = conv_g[o] / sqrtf(red[0]);
  __syncthreads();
  for (int e = tid; e < 384; e += 256) {
    const int ks = e >> 5, q = (e >> 3) & 3, j = e & 7;
    const int tap = ks >> 2, ci = (ks & 3) * 32 + q * 8 + j;
    Ap1[((mtg * 12 + ks) * 64 + q * 16 + r) * 8 + j] = f2bf(conv_v[(o * RESC + ci) * 3 + tap] * csc);
  }

  // ---- lc: norm over 80, pad K to 96 ----
  s = 0.f;
  for (int e = tid; e < CINC; e += 256) { float v = lc_v[o * CINC + e]; s += v * v; }
  red[tid] = s; __syncthreads();
  for (int off = 128; off > 0; off >>= 1) { if (tid < off) red[tid] += red[tid + off]; __syncthreads(); }
  const float lsc = lc_g[o] / sqrtf(red[0]);
  __syncthreads();
  for (int e = tid; e < CINP; e += 256) {
    const int ks = e >> 5, q = (e >> 3) & 3, j = e & 7;
    const float wv = (e < CINC) ? lc_v[o * CINC + e] * lsc : 0.f;
    Ap2[((mtg * 3 + ks) * 64 + q * 16 + r) * 8 + j] = f2bf(wv);
  }

  // ---- skip (rows 0..127) / out (rows 128..255): norm over 128 ----
  const float* vrow = (o < 128) ? (skip_v + o * 128) : (out_v + (o - 128) * 128);
  const float  gg   = (o < 128) ? skip_g[o] : out_g[o - 128];
  s = 0.f;
  for (int e = tid; e < 128; e += 256) { float v = vrow[e]; s += v * v; }
  red[tid] = s; __syncthreads();
  for (int off = 128; off > 0; off >>= 1) { if (tid < off) red[tid] += red[tid + off]; __syncthreads(); }
  const float ssc = gg / sqrtf(red[0]);
  for (int e = tid; e < 128; e += 256) {
    const int ks = e >> 5, q = (e >> 3) & 3, j = e & 7;
    Ap3[((mtg * 4 + ks) * 64 + q * 16 + r) * 8 + j] = f2bf(vrow[e] * ssc);
  }
}

// ---------------------------------------------------------------------------
// Fused block: conv(dil=2,causal) + cond GEMM -> gate (in-register) ->
// skip/out GEMMs. Grid: 4096 = 8 batches x 512 time-tiles of 64.
// Block: 256 thr = 4 waves.
// GEMM1/2: wave w owns PAIRED gate channels: a-mtiles {2w,2w+1} (h rows
// 32w..32w+31) and b-mtiles {8+2w,9+2w} (h rows 128+32w..). tanh*sigmoid is
// then computed wave-locally in f32 registers -> one LDS write of g, one
// barrier (was: two activation phases + product phase + 2 barriers).
// GEMM3: wave w owns output rows 64w.. (waves 0,1 skip; 2,3 out) as before.
// NOTE: plain __launch_bounds__(256). Adding a min-waves clause (R1: ",5")
// capped regs below the ~150 combined VGPR+AGPR this kernel needs and
// spilled the accumulators to scratch: WRITE_SIZE 263MB->1.59GB, 3.3x slower.
// ---------------------------------------------------------------------------
__global__ __launch_bounds__(256) void fused_block_kernel(
    const float* __restrict__ x, const float* __restrict__ cond,
    const float* __restrict__ conv_b, const float* __restrict__ skip_b,
    const float* __restrict__ out_b,
    const ushort* __restrict__ Ap1, const ushort* __restrict__ Ap2,
    const ushort* __restrict__ Ap3,
    float* __restrict__ out) {
  const int tid  = threadIdx.x;
  const int w    = tid >> 6;
  const int lane = tid & 63;
  const int q    = lane >> 4;   // MFMA quad
  const int n    = lane & 15;   // MFMA column (time within 16-tile)
  const int blk  = blockIdx.x;
  const int b    = blk >> 9;
  const int t0   = (blk & 511) << 6;

  __shared__ __align__(128) char smem[LDS_BYTES];
  char* xs = smem;            // [68][136 ushort] x-tile (rows = t - (t0-4)), swizzled
  char* cs = smem + CS_OFF;   // [64][104 ushort] cond-tile, swizzled
  char* gs = smem;            // [64][136 ushort] g-tile, aliases xs after barrier

  // ================= stage x tile (transpose [c][t] -> [t][c], bf16) =======
  {
    const int g4 = tid >> 3;            // 0..31 -> channels 4*g4..+3
    const int c0 = g4 << 2;
    const int tt = (tid & 7) << 3;      // 8 timesteps per thread
    const float* xp = x + ((size_t)b * RESC + c0) * T_N + t0 + tt;
    float va[4][8];
#pragma unroll
    for (int rr = 0; rr < 4; ++rr) {
      const float4* rp = (const float4*)(xp + (size_t)rr * T_N);
      const float4 a0 = rp[0], a1 = rp[1];
      va[rr][0] = a0.x; va[rr][1] = a0.y; va[rr][2] = a0.z; va[rr][3] = a0.w;
      va[rr][4] = a1.x; va[rr][5] = a1.y; va[rr][6] = a1.z; va[rr][7] = a1.w;
    }
#pragma unroll
    for (int ss = 0; ss < 8; ++ss) {
      const unsigned lo = (unsigned)f2bf(va[0][ss]) | ((unsigned)f2bf(va[1][ss]) << 16);
      const unsigned hi = (unsigned)f2bf(va[2][ss]) | ((unsigned)f2bf(va[3][ss]) << 16);
      *(uint2*)lds_at(xs, HALO + tt + ss, XSTR_B, c0 * 2) = make_uint2(lo, hi);
    }
  }
  // halo rows 0..3 = t0-4..t0-1 (zeros at sequence start = causal left-pad)
  if (tid < RESC) {
    float h0 = 0.f, h1 = 0.f, h2 = 0.f, h3 = 0.f;
    if (t0 > 0) {
      const float4 hv = *(const float4*)(x + ((size_t)b * RESC + tid) * T_N + t0 - 4);
      h0 = hv.x; h1 = hv.y; h2 = hv.z; h3 = hv.w;
    }
    *(ushort*)lds_at(xs, 0, XSTR_B, tid * 2) = f2bf(h0);
    *(ushort*)lds_at(xs, 1, XSTR_B, tid * 2) = f2bf(h1);
    *(ushort*)lds_at(xs, 2, XSTR_B, tid * 2) = f2bf(h2);
    *(ushort*)lds_at(xs, 3, XSTR_B, tid * 2) = f2bf(h3);
  }
  // ================= stage cond tile ([c][t] -> [t][c], pad 80->96) ========
  if (tid < 160) {
    const int g4 = tid >> 3;            // 0..19
    const int c0 = g4 << 2;
    const int tt = (tid & 7) << 3;
    const float* cp = cond + ((size_t)b * CINC + c0) * T_N + t0 + tt;
    float va[4][8];
#pragma unroll
    for (int rr = 0; rr < 4; ++rr) {
      const float4* rp = (const float4*)(cp + (size_t)rr * T_N);
      const float4 a0 = rp[0], a1 = rp[1];
      va[rr][0] = a0.x; va[rr][1] = a0.y; va[rr][2] = a0.z; va[rr][3] = a0.w;
      va[rr][4] = a1.x; va[rr][5] = a1.y; va[rr][6] = a1.z; va[rr][7] = a1.w;
    }
#pragma unroll
    for (int ss = 0; ss < 8; ++ss) {
      const unsigned lo = (unsigned)f2bf(va[0][ss]) | ((unsigned)f2bf(va[1][ss]) << 16);
      const unsigned hi = (unsigned)f2bf(va[2][ss]) | ((unsigned)f2bf(va[3][ss]) << 16);
      *(uint2*)lds_at(cs, tt + ss, CSTR_B, c0 * 2) = make_uint2(lo, hi);
    }
  } else {
    const int e0 = tid - 160;           // zero-fill ushort cols 80..95 (k-pad)
    for (int z = e0; z < 512; z += 96) {
      const int row = z >> 3, c = z & 7;
      *(unsigned int*)lds_at(cs, row, CSTR_B, 160 + c * 4) = 0u;
    }
  }
  __syncthreads();

  // ================= GEMM1 (conv, K=384) + GEMM2 (lc, K=96) into acc ======
  // acc[0..1] = a-half (h rows 32w + 16*mt + ...), acc[2..3] = b-half.
  const int mtile[4] = {2 * w, 2 * w + 1, 8 + 2 * w, 9 + 2 * w};
  f32x4 acc[4][4];
#pragma unroll
  for (int mt = 0; mt < 4; ++mt) {
    const float4 cb = *(const float4*)(conv_b + mtile[mt] * 16 + q * 4);
#pragma unroll
    for (int nt = 0; nt < 4; ++nt) acc[mt][nt] = (f32x4){cb.x, cb.y, cb.z, cb.w};
  }
#pragma unroll
  for (int ks = 0; ks < 12; ++ks) {
    const int tap = ks >> 2;
    const int cbyte = ((ks & 3) << 6);
    short8 af[4], bfr[4];
#pragma unroll
    for (int mt = 0; mt < 4; ++mt)
      af[mt] = *(const short8*)(Ap1 + ((mtile[mt] * 12 + ks) * 64 + lane) * 8);
#pragma unroll
    for (int nt = 0; nt < 4; ++nt)
      bfr[nt] = *(const short8*)lds_at(xs, nt * 16 + n + tap * 2, XSTR_B, cbyte + q * 16);
#pragma unroll
    for (int mt = 0; mt < 4; ++mt)
#pragma unroll
      for (int nt = 0; nt < 4; ++nt)
        acc[mt][nt] = __builtin_amdgcn_mfma_f32_16x16x32_bf16(af[mt], bfr[nt], acc[mt][nt], 0, 0, 0);
  }
#pragma unroll
  for (int ks = 0; ks < 3; ++ks) {
    short8 af[4], bfr[4];
#pragma unroll
    for (int mt = 0; mt < 4; ++mt)
      af[mt] = *(const short8*)(Ap2 + ((mtile[mt] * 3 + ks) * 64 + lane) * 8);
#pragma unroll
    for (int nt = 0; nt < 4; ++nt)
      bfr[nt] = *(const short8*)lds_at(cs, nt * 16 + n, CSTR_B, ks * 64 + q * 16);
#pragma unroll
    for (int mt = 0; mt < 4; ++mt)
#pragma unroll
      for (int nt = 0; nt < 4; ++nt)
        acc[mt][nt] = __builtin_amdgcn_mfma_f32_16x16x32_bf16(af[mt], bfr[nt], acc[mt][nt], 0, 0, 0);
  }
  __syncthreads();   // all xs/cs reads done; safe to overwrite aliased region

  // ================= g = tanh(a)*sigmoid(b) in registers -> LDS ===========
#pragma unroll
  for (int mt = 0; mt < 2; ++mt)
#pragma unroll
    for (int nt = 0; nt < 4; ++nt) {
      const f32x4 va = acc[mt][nt];
      const f32x4 vb = acc[mt + 2][nt];
      float r[4];
#pragma unroll
      for (int i = 0; i < 4; ++i) {
        const float ta = 1.f - 2.f / (__expf(2.f * va[i]) + 1.f);
        const float sb = 1.f / (1.f + __expf(-vb[i]));
        r[i] = ta * sb;
      }
      const unsigned lo = (unsigned)f2bf(r[0]) | ((unsigned)f2bf(r[1]) << 16);
      const unsigned hi = (unsigned)f2bf(r[2]) | ((unsigned)f2bf(r[3]) << 16);
      // gate channel = 32w + 16*mt + 4*q + i ; byte col = 2*channel
      *(uint2*)lds_at(gs, nt * 16 + n, XSTR_B, 64 * w + 32 * mt + 8 * q) = make_uint2(lo, hi);
    }
  __syncthreads();

  // ================= GEMM3: [skip;out] = Wso @ g, K=128 ===================
  const int colbase = (w & 1) << 6;
  {
    const float* bias = (w < 2) ? skip_b : out_b;
#pragma unroll
    for (int mt = 0; mt < 4; ++mt) {
      const float4 bb = *(const float4*)(bias + colbase + mt * 16 + q * 4);
#pragma unroll
      for (int nt = 0; nt < 4; ++nt) acc[mt][nt] = (f32x4){bb.x, bb.y, bb.z, bb.w};
    }
#pragma unroll
    for (int ks = 0; ks < 4; ++ks) {
      short8 af[4], bfr[4];
#pragma unroll
      for (int mt = 0; mt < 4; ++mt)
        af[mt] = *(const short8*)(Ap3 + ((w * 4 + mt) * 4 + ks) * 512 + lane * 8);
#pragma unroll
      for (int nt = 0; nt < 4; ++nt)
        bfr[nt] = *(const short8*)lds_at(gs, nt * 16 + n, XSTR_B, ks * 64 + q * 16);
#pragma unroll
      for (int mt = 0; mt < 4; ++mt)
#pragma unroll
        for (int nt = 0; nt < 4; ++nt)
          acc[mt][nt] = __builtin_amdgcn_mfma_f32_16x16x32_bf16(af[mt], bfr[nt], acc[mt][nt], 0, 0, 0);
    }
  }

  // ================= epilogue: stores (s for waves 0,1; o+residual 2,3) ===
#pragma unroll
  for (int mt = 0; mt < 4; ++mt)
#pragma unroll
    for (int nt = 0; nt < 4; ++nt) {
      const int ch = colbase + mt * 16 + q * 4;
      const int t  = t0 + nt * 16 + n;
      const f32x4 v = acc[mt][nt];
      if (w < 2) {
        float* dst = out + OFF_S + ((size_t)(b * RESC + ch)) * T_N + t;
#pragma unroll
        for (int i = 0; i < 4; ++i) dst[(size_t)i * T_N] = v[i];
      } else {
        const float* xr = x + ((size_t)(b * RESC + ch)) * T_N + t;
        float* dst = out + ((size_t)(b * RESC + ch)) * T_N + t;
#pragma unroll
        for (int i = 0; i < 4; ++i) dst[(size_t)i * T_N] = v[i] + xr[(size_t)i * T_N];
      }
    }
}

extern "C" void kernel_launch(void* const* d_in, const int* in_sizes, int n_in,
                              void* d_out, int out_size, void* d_ws, size_t ws_size,
                              hipStream_t stream) {
  const float* x      = (const float*)d_in[0];
  const float* cond   = (const float*)d_in[1];
  const float* conv_v = (const float*)d_in[2];
  const float* conv_g = (const float*)d_in[3];
  const float* conv_b = (const float*)d_in[4];
  const float* lc_v   = (const float*)d_in[5];
  const float* lc_g   = (const float*)d_in[6];
  const float* skip_v = (const float*)d_in[7];
  const float* skip_g = (const float*)d_in[8];
  const float* skip_b = (const float*)d_in[9];
  const float* out_v  = (const float*)d_in[10];
  const float* out_g  = (const float*)d_in[11];
  const float* out_b  = (const float*)d_in[12];

  ushort* Ap1 = (ushort*)d_ws;
  ushort* Ap2 = Ap1 + AP1_ELEMS;
  ushort* Ap3 = Ap2 + AP2_ELEMS;

  hipLaunchKernelGGL(wn_pack_kernel, dim3(256), dim3(256), 0, stream,
                     conv_v, conv_g, lc_v, lc_g, skip_v, skip_g, out_v, out_g,
                     Ap1, Ap2, Ap3);
  hipLaunchKernelGGL(fused_block_kernel, dim3(4096), dim3(256), 0, stream,
                     x, cond, conv_b, skip_b, out_b, Ap1, Ap2, Ap3, (float*)d_out);
}

// Round 3
// 504.190 us; speedup vs baseline: 1.9149x; 1.0776x over previous
//
#include <hip/hip_runtime.h>

#define B_N   8
#define T_N   32768
#define RESC  128
#define GATEC 256
#define CINC  80
#define CINP  96
#define NT    64
#define HALO  4
#define XROWS 68

#define XSTR_B 272           /* x-tile byte stride: 136 ushorts */
#define CSTR_B 208           /* cond-tile byte stride: 104 ushorts (pad kills 8-way) */
#define CS_OFF 18496         /* 68*272 bytes */
#define LDS_BYTES (18496 + 13312)   /* xs + cs = 31808 B */

#define AP1_ELEMS (16*12*512)  /* 98304 bf16 */
#define AP2_ELEMS (16*3*512)   /* 24576 */
#define AP3_ELEMS (16*4*512)   /* 32768 */

#define OFF_S ((size_t)B_N * RESC * T_N)  /* s output offset in floats */

typedef __attribute__((ext_vector_type(8))) short short8;
typedef __attribute__((ext_vector_type(4))) float f32x4;

__device__ __forceinline__ ushort f2bf(float f) {
  union { float f; unsigned int u; } c; c.f = f;
  unsigned int u = c.u;
  u += 0x7fffu + ((u >> 16) & 1u);   // round-to-nearest-even
  return (ushort)(u >> 16);
}

// XOR-swizzled LDS addressing. Bijective within each 8-row group because
// 8*stride is a multiple of 128 B for both strides used (272, 208).
// Spreads the 8 t-groups of a staging wave across 8 bank quads; keeps 16B
// blocks intact so ds_read_b128 stays legal. Same formula on write and read.
__device__ __forceinline__ char* lds_at(char* base, int row, int strB, int colB) {
  int off = row * strB + colB;
  off ^= ((row >> 3) & 7) << 4;
  return base + off;
}

// ---------------------------------------------------------------------------
// Prep: weight-norm (fp32) -> bf16 -> pack into MFMA A-fragment order.
// A-frag layout (16x16x32 bf16, m89-verified): A[m = lane&15][k = (lane>>4)*8 + j]
// Apack[((mtile*KS + ks)*64 + lane)*8 + j]
// ---------------------------------------------------------------------------
__global__ __launch_bounds__(256) void wn_pack_kernel(
    const float* __restrict__ conv_v, const float* __restrict__ conv_g,
    const float* __restrict__ lc_v,  const float* __restrict__ lc_g,
    const float* __restrict__ skip_v,const float* __restrict__ skip_g,
    const float* __restrict__ out_v, const float* __restrict__ out_g,
    ushort* __restrict__ Ap1, ushort* __restrict__ Ap2, ushort* __restrict__ Ap3) {
  const int o   = blockIdx.x;   // output channel 0..255
  const int tid = threadIdx.x;  // 0..255
  const int mtg = o >> 4, r = o & 15;
  __shared__ float red[256];

  // ---- conv: norm over 128*3 ----
  float s = 0.f;
  for (int e = tid; e < RESC * 3; e += 256) { float v = conv_v[o * RESC * 3 + e]; s += v * v; }
  red[tid] = s; __syncthreads();
  for (int off = 128; off > 0; off >>= 1) { if (tid < off) red[tid] += red[tid + off]; __syncthreads(); }
  const float csc = conv_g[o] / sqrtf(red[0]);
  __syncthreads();
  for (int e = tid; e < 384; e += 256) {
    const int ks = e >> 5, q = (e >> 3) & 3, j = e & 7;
    const int tap = ks >> 2, ci = (ks & 3) * 32 + q * 8 + j;
    Ap1[((mtg * 12 + ks) * 64 + q * 16 + r) * 8 + j] = f2bf(conv_v[(o * RESC + ci) * 3 + tap] * csc);
  }

  // ---- lc: norm over 80, pad K to 96 ----
  s = 0.f;
  for (int e = tid; e < CINC; e += 256) { float v = lc_v[o * CINC + e]; s += v * v; }
  red[tid] = s; __syncthreads();
  for (int off = 128; off > 0; off >>= 1) { if (tid < off) red[tid] += red[tid + off]; __syncthreads(); }
  const float lsc = lc_g[o] / sqrtf(red[0]);
  __syncthreads();
  for (int e = tid; e < CINP; e += 256) {
    const int ks = e >> 5, q = (e >> 3) & 3, j = e & 7;
    const float wv = (e < CINC) ? lc_v[o * CINC + e] * lsc : 0.f;
    Ap2[((mtg * 3 + ks) * 64 + q * 16 + r) * 8 + j] = f2bf(wv);
  }

  // ---- skip (rows 0..127) / out (rows 128..255): norm over 128 ----
  const float* vrow = (o < 128) ? (skip_v + o * 128) : (out_v + (o - 128) * 128);
  const float  gg   = (o < 128) ? skip_g[o] : out_g[o - 128];
  s = 0.f;
  for (int e = tid; e < 128; e += 256) { float v = vrow[e]; s += v * v; }
  red[tid] = s; __syncthreads();
  for (int off = 128; off > 0; off >>= 1) { if (tid < off) red[tid] += red[tid + off]; __syncthreads(); }
  const float ssc = gg / sqrtf(red[0]);
  for (int e = tid; e < 128; e += 256) {
    const int ks = e >> 5, q = (e >> 3) & 3, j = e & 7;
    Ap3[((mtg * 4 + ks) * 64 + q * 16 + r) * 8 + j] = f2bf(vrow[e] * ssc);
  }
}

// ---------------------------------------------------------------------------
// Fused block, 8-wave version. Grid: 4096 = 8 batches x 512 time-tiles of 64.
// Block: 512 thr = 8 waves.
// Register story (THE lever on this latency-bound kernel): per-wave output
// tile halved vs the 4-wave version -> acc is f32x4[2][4] = 32 AGPRs instead
// of 64. Unified-file budget 512/wave: arch VGPR + 32 must be <= 128 to get
// 4 waves/SIMD (2 resident blocks/CU). R1 lesson: never force with a
// min-waves launch_bounds clause (spilled acc -> 1.59 GB scratch traffic).
// GEMM1/2: wave w owns a-mtile w (gate ch 16w..16w+15) + b-mtile 8+w
//   (ch 128+16w..); tanh(a)*sigmoid(b) computed in registers, one LDS write.
// GEMM3: wave w owns skip-mtile w and out-mtile 8+w (16 ch each).
// Staging is wave-parallel: tid<256 x-tile, 256..447 cond(+pad), 448+ halo.
// ---------------------------------------------------------------------------
__global__ __launch_bounds__(512) void fused_block_kernel(
    const float* __restrict__ x, const float* __restrict__ cond,
    const float* __restrict__ conv_b, const float* __restrict__ skip_b,
    const float* __restrict__ out_b,
    const ushort* __restrict__ Ap1, const ushort* __restrict__ Ap2,
    const ushort* __restrict__ Ap3,
    float* __restrict__ out) {
  const int tid  = threadIdx.x;
  const int w    = tid >> 6;    // 0..7
  const int lane = tid & 63;
  const int q    = lane >> 4;   // MFMA quad
  const int n    = lane & 15;   // MFMA column (time within 16-tile)
  const int blk  = blockIdx.x;
  const int b    = blk >> 9;
  const int t0   = (blk & 511) << 6;

  __shared__ __align__(128) char smem[LDS_BYTES];
  char* xs = smem;            // [68][136 ushort] x-tile (rows = t - (t0-4)), swizzled
  char* cs = smem + CS_OFF;   // [64][104 ushort] cond-tile, swizzled
  char* gs = smem;            // [64][136 ushort] g-tile, aliases xs after barrier

  // ================= staging, wave-parallel ================================
  if (tid < 256) {
    // x tile: transpose [c][t] -> [t][c], 4 channels x 8 timesteps per thread
    const int c0 = (tid >> 3) << 2;
    const int tt = (tid & 7) << 3;
    const float* xp = x + ((size_t)b * RESC + c0) * T_N + t0 + tt;
    float va[4][8];
#pragma unroll
    for (int rr = 0; rr < 4; ++rr) {
      const float4* rp = (const float4*)(xp + (size_t)rr * T_N);
      const float4 a0 = rp[0], a1 = rp[1];
      va[rr][0] = a0.x; va[rr][1] = a0.y; va[rr][2] = a0.z; va[rr][3] = a0.w;
      va[rr][4] = a1.x; va[rr][5] = a1.y; va[rr][6] = a1.z; va[rr][7] = a1.w;
    }
#pragma unroll
    for (int ss = 0; ss < 8; ++ss) {
      const unsigned lo = (unsigned)f2bf(va[0][ss]) | ((unsigned)f2bf(va[1][ss]) << 16);
      const unsigned hi = (unsigned)f2bf(va[2][ss]) | ((unsigned)f2bf(va[3][ss]) << 16);
      *(uint2*)lds_at(xs, HALO + tt + ss, XSTR_B, c0 * 2) = make_uint2(lo, hi);
    }
  } else if (tid < 448) {
    // cond tile (+ zero-pad cols 80..95): 24 channel-groups x 8 t-groups
    const int e  = tid - 256;
    const int c0 = (e >> 3) << 2;       // 0,4,...,92
    const int tt = (e & 7) << 3;
    if (c0 < CINC) {
      const float* cp = cond + ((size_t)b * CINC + c0) * T_N + t0 + tt;
      float va[4][8];
#pragma unroll
      for (int rr = 0; rr < 4; ++rr) {
        const float4* rp = (const float4*)(cp + (size_t)rr * T_N);
        const float4 a0 = rp[0], a1 = rp[1];
        va[rr][0] = a0.x; va[rr][1] = a0.y; va[rr][2] = a0.z; va[rr][3] = a0.w;
        va[rr][4] = a1.x; va[rr][5] = a1.y; va[rr][6] = a1.z; va[rr][7] = a1.w;
      }
#pragma unroll
      for (int ss = 0; ss < 8; ++ss) {
        const unsigned lo = (unsigned)f2bf(va[0][ss]) | ((unsigned)f2bf(va[1][ss]) << 16);
        const unsigned hi = (unsigned)f2bf(va[2][ss]) | ((unsigned)f2bf(va[3][ss]) << 16);
        *(uint2*)lds_at(cs, tt + ss, CSTR_B, c0 * 2) = make_uint2(lo, hi);
      }
    } else {
#pragma unroll
      for (int ss = 0; ss < 8; ++ss)
        *(uint2*)lds_at(cs, tt + ss, CSTR_B, c0 * 2) = make_uint2(0u, 0u);
    }
  } else {
    // halo rows 0..3 = t0-4..t0-1 (zeros at sequence start): 2 channels/thread
    const int e   = tid - 448;          // 0..63
    const int ch0 = e << 1;
    float h0[4] = {0.f, 0.f, 0.f, 0.f}, h1[4] = {0.f, 0.f, 0.f, 0.f};
    if (t0 > 0) {
      const float4 v0 = *(const float4*)(x + ((size_t)b * RESC + ch0) * T_N + t0 - 4);
      const float4 v1 = *(const float4*)(x + ((size_t)b * RESC + ch0 + 1) * T_N + t0 - 4);
      h0[0] = v0.x; h0[1] = v0.y; h0[2] = v0.z; h0[3] = v0.w;
      h1[0] = v1.x; h1[1] = v1.y; h1[2] = v1.z; h1[3] = v1.w;
    }
#pragma unroll
    for (int rr = 0; rr < 4; ++rr) {
      const unsigned pk = (unsigned)f2bf(h0[rr]) | ((unsigned)f2bf(h1[rr]) << 16);
      *(unsigned int*)lds_at(xs, rr, XSTR_B, ch0 * 2) = pk;
    }
  }
  __syncthreads();

  // ================= GEMM1 (conv, K=384) + GEMM2 (lc, K=96) ==============
  // acc[0] = a-half (gate ch 16w+...), acc[1] = b-half (gate ch 128+16w+...)
  const int mtA = w, mtB = 8 + w;
  f32x4 acc[2][4];
  {
    const float4 ca = *(const float4*)(conv_b + mtA * 16 + q * 4);
    const float4 cb = *(const float4*)(conv_b + mtB * 16 + q * 4);
#pragma unroll
    for (int nt = 0; nt < 4; ++nt) {
      acc[0][nt] = (f32x4){ca.x, ca.y, ca.z, ca.w};
      acc[1][nt] = (f32x4){cb.x, cb.y, cb.z, cb.w};
    }
  }
#pragma unroll
  for (int ks = 0; ks < 12; ++ks) {
    const int tap = ks >> 2;
    const int cbyte = ((ks & 3) << 6);
    const short8 af0 = *(const short8*)(Ap1 + ((mtA * 12 + ks) * 64 + lane) * 8);
    const short8 af1 = *(const short8*)(Ap1 + ((mtB * 12 + ks) * 64 + lane) * 8);
    short8 bfr[4];
#pragma unroll
    for (int nt = 0; nt < 4; ++nt)
      bfr[nt] = *(const short8*)lds_at(xs, nt * 16 + n + tap * 2, XSTR_B, cbyte + q * 16);
#pragma unroll
    for (int nt = 0; nt < 4; ++nt) {
      acc[0][nt] = __builtin_amdgcn_mfma_f32_16x16x32_bf16(af0, bfr[nt], acc[0][nt], 0, 0, 0);
      acc[1][nt] = __builtin_amdgcn_mfma_f32_16x16x32_bf16(af1, bfr[nt], acc[1][nt], 0, 0, 0);
    }
  }
#pragma unroll
  for (int ks = 0; ks < 3; ++ks) {
    const short8 af0 = *(const short8*)(Ap2 + ((mtA * 3 + ks) * 64 + lane) * 8);
    const short8 af1 = *(const short8*)(Ap2 + ((mtB * 3 + ks) * 64 + lane) * 8);
    short8 bfr[4];
#pragma unroll
    for (int nt = 0; nt < 4; ++nt)
      bfr[nt] = *(const short8*)lds_at(cs, nt * 16 + n, CSTR_B, ks * 64 + q * 16);
#pragma unroll
    for (int nt = 0; nt < 4; ++nt) {
      acc[0][nt] = __builtin_amdgcn_mfma_f32_16x16x32_bf16(af0, bfr[nt], acc[0][nt], 0, 0, 0);
      acc[1][nt] = __builtin_amdgcn_mfma_f32_16x16x32_bf16(af1, bfr[nt], acc[1][nt], 0, 0, 0);
    }
  }
  __syncthreads();   // all xs/cs reads done; safe to overwrite aliased region

  // ================= g = tanh(a)*sigmoid(b) in registers -> LDS ===========
#pragma unroll
  for (int nt = 0; nt < 4; ++nt) {
    const f32x4 va = acc[0][nt];
    const f32x4 vb = acc[1][nt];
    float r[4];
#pragma unroll
    for (int i = 0; i < 4; ++i) {
      const float ta = 1.f - 2.f / (__expf(2.f * va[i]) + 1.f);
      const float sb = 1.f / (1.f + __expf(-vb[i]));
      r[i] = ta * sb;
    }
    const unsigned lo = (unsigned)f2bf(r[0]) | ((unsigned)f2bf(r[1]) << 16);
    const unsigned hi = (unsigned)f2bf(r[2]) | ((unsigned)f2bf(r[3]) << 16);
    // gate channel = 16w + 4q + i ; byte col = 2*channel
    *(uint2*)lds_at(gs, nt * 16 + n, XSTR_B, (16 * w + 4 * q) * 2) = make_uint2(lo, hi);
  }
  __syncthreads();

  // ================= GEMM3: [skip;out] = Wso @ g, K=128 ===================
  // acc[0] = skip ch 16w+..., acc[1] = out ch 16w+... (Ap3 mtiles w, 8+w)
  {
    const float4 bs = *(const float4*)(skip_b + w * 16 + q * 4);
    const float4 bo = *(const float4*)(out_b  + w * 16 + q * 4);
#pragma unroll
    for (int nt = 0; nt < 4; ++nt) {
      acc[0][nt] = (f32x4){bs.x, bs.y, bs.z, bs.w};
      acc[1][nt] = (f32x4){bo.x, bo.y, bo.z, bo.w};
    }
  }
#pragma unroll
  for (int ks = 0; ks < 4; ++ks) {
    const short8 af0 = *(const short8*)(Ap3 + ((w * 4 + ks) * 64 + lane) * 8);
    const short8 af1 = *(const short8*)(Ap3 + (((8 + w) * 4 + ks) * 64 + lane) * 8);
    short8 bfr[4];
#pragma unroll
    for (int nt = 0; nt < 4; ++nt)
      bfr[nt] = *(const short8*)lds_at(gs, nt * 16 + n, XSTR_B, ks * 64 + q * 16);
#pragma unroll
    for (int nt = 0; nt < 4; ++nt) {
      acc[0][nt] = __builtin_amdgcn_mfma_f32_16x16x32_bf16(af0, bfr[nt], acc[0][nt], 0, 0, 0);
      acc[1][nt] = __builtin_amdgcn_mfma_f32_16x16x32_bf16(af1, bfr[nt], acc[1][nt], 0, 0, 0);
    }
  }

  // ================= epilogue: skip store + out(+residual) store ==========
  const int ch = 16 * w + 4 * q;
#pragma unroll
  for (int nt = 0; nt < 4; ++nt) {
    const int t = t0 + nt * 16 + n;
    const f32x4 vs = acc[0][nt];
    const f32x4 vo = acc[1][nt];
    float* ds = out + OFF_S + ((size_t)(b * RESC + ch)) * T_N + t;
#pragma unroll
    for (int i = 0; i < 4; ++i) ds[(size_t)i * T_N] = vs[i];
    const float* xr = x + ((size_t)(b * RESC + ch)) * T_N + t;
    float* dо = out + ((size_t)(b * RESC + ch)) * T_N + t;
#pragma unroll
    for (int i = 0; i < 4; ++i) dо[(size_t)i * T_N] = vo[i] + xr[(size_t)i * T_N];
  }
}

extern "C" void kernel_launch(void* const* d_in, const int* in_sizes, int n_in,
                              void* d_out, int out_size, void* d_ws, size_t ws_size,
                              hipStream_t stream) {
  const float* x      = (const float*)d_in[0];
  const float* cond   = (const float*)d_in[1];
  const float* conv_v = (const float*)d_in[2];
  const float* conv_g = (const float*)d_in[3];
  const float* conv_b = (const float*)d_in[4];
  const float* lc_v   = (const float*)d_in[5];
  const float* lc_g   = (const float*)d_in[6];
  const float* skip_v = (const float*)d_in[7];
  const float* skip_g = (const float*)d_in[8];
  const float* skip_b = (const float*)d_in[9];
  const float* out_v  = (const float*)d_in[10];
  const float* out_g  = (const float*)d_in[11];
  const float* out_b  = (const float*)d_in[12];

  ushort* Ap1 = (ushort*)d_ws;
  ushort* Ap2 = Ap1 + AP1_ELEMS;
  ushort* Ap3 = Ap2 + AP2_ELEMS;

  hipLaunchKernelGGL(wn_pack_kernel, dim3(256), dim3(256), 0, stream,
                     conv_v, conv_g, lc_v, lc_g, skip_v, skip_g, out_v, out_g,
                     Ap1, Ap2, Ap3);
  hipLaunchKernelGGL(fused_block_kernel, dim3(4096), dim3(512), 0, stream,
                     x, cond, conv_b, skip_b, out_b, Ap1, Ap2, Ap3, (float*)d_out);
}